// Round 13
// baseline (486.135 us; speedup 1.0000x reference)
//
#include <hip/hip_runtime.h>

// RelationalDelayGNNStage: N=20000, E=500000, D=256, T=4, NTYPES=3
// Round 26: de-fragmented aggregate. R25 (8-wave gemm) is kept — new best
// 478.8us, gemm t3 52.8us at structural floor (~2100cy/iter across 4
// geometries; wave-count lever weak: 2x waves -> +11%). Pivot to aggregate
// (~185us): R18's dedup walked each (dst,etype) run (avg 8.3 edges) as 4
// hop sub-segment loops of ~2 edges — pure tail code, no MLP. Now: ONE
// fused loop over [b0,b4) per (dst,etype); hop routing branchless via
// selector fma (aHk += r * (idx in [bk,bk+1) ? 1 : 0); adding exact 0.0
// for non-members; per-acc order preserved). Routing only emitted for
// live channels: t=3 pays none (pure sum), t=0 pays 3. fp32 pair-tree
// reorder only — within absmax budget. GEMM/CSR/scans/epilogue frozen.
// Numerics: f16 operands (A 2^-6, W 2^4), fp32 accum.

#define NN 20000
#define NROWP 20032   // 64-row-tile padded row count
#define NE 500000
#define DD 256
#define TT 4
#define NT 3
#define SCANN (12 * NN)          // 240000 sub-channel counters
#define NB12 235                 // ceil(SCANN / 1024)

typedef _Float16 f16;
typedef _Float16 f16x8 __attribute__((ext_vector_type(8)));
typedef _Float16 f16x4v __attribute__((ext_vector_type(4)));
typedef float f32x4 __attribute__((ext_vector_type(4)));

__device__ __forceinline__ void gload_lds16(const void* g, void* l) {
  __builtin_amdgcn_global_load_lds(
      (const __attribute__((address_space(1))) unsigned int*)g,
      (__attribute__((address_space(3))) unsigned int*)l, 16, 0, 0);
}

// ---------------- 12-sub-channel CSR build ----------------
// key = ((dst*3 + etype) << 2) | (hop-1);  hop in 1..4

__global__ void k_hist(const int* __restrict__ ei, const int* __restrict__ ea,
                       int* __restrict__ cnt12) {
  int e = blockIdx.x * 256 + threadIdx.x;
  if (e >= NE) return;
  int dst = ei[NE + e];
  int hop = ea[2 * e];
  int et  = ea[2 * e + 1];
  atomicAdd(&cnt12[((dst * 3 + et) << 2) | (hop - 1)], 1);
}

// hierarchical scan over cnt12[12N] -> crow12 (exclusive), ccur copy

__global__ __launch_bounds__(1024) void k_scan_blk(
    const int* __restrict__ cnt, int* __restrict__ crow, int* __restrict__ bsum) {
  __shared__ int wsum[16];
  int tid = threadIdx.x, lane = tid & 63, wv = tid >> 6;
  int i = blockIdx.x * 1024 + tid;
  int v = (i < SCANN) ? cnt[i] : 0;
  int s = v;
#pragma unroll
  for (int off = 1; off < 64; off <<= 1) {
    int t = __shfl_up(s, off, 64);
    if (lane >= off) s += t;
  }
  if (lane == 63) wsum[wv] = s;
  __syncthreads();
  if (wv == 0) {
    int ws = (lane < 16) ? wsum[lane] : 0;
#pragma unroll
    for (int off = 1; off < 16; off <<= 1) {
      int t = __shfl_up(ws, off, 64);
      if (lane >= off) ws += t;
    }
    if (lane < 16) wsum[lane] = ws;
  }
  __syncthreads();
  int excl = ((wv == 0) ? 0 : wsum[wv - 1]) + s - v;
  if (i < SCANN) crow[i] = excl;
  if (tid == 1023) bsum[blockIdx.x] = wsum[15];
}

__global__ __launch_bounds__(256) void k_scan_top(
    int* __restrict__ bsum, int* __restrict__ crow) {
  __shared__ int wsum2[4];
  int tid = threadIdx.x, lane = tid & 63, wv = tid >> 6;
  int v = (tid < NB12) ? bsum[tid] : 0;
  int s = v;
#pragma unroll
  for (int off = 1; off < 64; off <<= 1) {
    int t = __shfl_up(s, off, 64);
    if (lane >= off) s += t;
  }
  if (lane == 63) wsum2[wv] = s;
  __syncthreads();
  int add = 0;
#pragma unroll
  for (int w = 0; w < 4; w++) add += (w < wv) ? wsum2[w] : 0;
  int excl = add + s - v;
  if (tid < NB12) bsum[tid] = excl;
  if (tid == NB12 - 1) crow[SCANN] = excl + v;
}

__global__ __launch_bounds__(1024) void k_scan_fix(
    int* __restrict__ crow, int* __restrict__ ccur, const int* __restrict__ bsum) {
  int i = blockIdx.x * 1024 + threadIdx.x;
  if (i >= SCANN) return;
  int val = crow[i] + bsum[blockIdx.x];
  crow[i] = val;
  ccur[i] = val;
}

__global__ void k_scatter(const int* __restrict__ ei, const int* __restrict__ ea,
                          int* __restrict__ ccur, int* __restrict__ crec) {
  int e = blockIdx.x * 256 + threadIdx.x;
  if (e >= NE) return;
  int src = ei[e];
  int dst = ei[NE + e];
  int hop = ea[2 * e];
  int et  = ea[2 * e + 1];
  int pos = atomicAdd(&ccur[((dst * 3 + et) << 2) | (hop - 1)], 1);
  crec[pos] = src;
}

// per-(node,channel) counts for the GEMM bias epilogue, from crow12

__global__ __launch_bounds__(256) void k_cnt6(
    const int* __restrict__ crow12, int* __restrict__ cnt) {
  int v = blockIdx.x * 256 + threadIdx.x;
  if (v >= NN) return;
  int h2 = 0, h3 = 0, h4 = 0;
#pragma unroll
  for (int et = 0; et < 3; et++) {
    int base = (v * 3 + et) * 4;
    int b0 = crow12[base], b1 = crow12[base + 1], b2 = crow12[base + 2],
        b3 = crow12[base + 3], b4 = crow12[base + 4];
    cnt[et * NN + v] = b4 - b0;
    h2 += b2 - b1;
    h3 += b3 - b2;
    h4 += b4 - b3;
  }
  cnt[3 * NN + v] = h2;
  cnt[4 * NN + v] = h3;
  cnt[5 * NN + v] = h4;
}

// ---------------- W: fp32 -> transposed f16 (scale 2^4), LDS-tiled ----------------

__global__ __launch_bounds__(256) void k_wsplit(
    const float* __restrict__ W_edge, const float* __restrict__ W_hop,
    f16* __restrict__ Wout) {
  __shared__ float tile[64][65];
  int w = blockIdx.z;
  int tk = blockIdx.x * 64;
  int tn = blockIdx.y * 64;
  const float* src = (w < 12) ? (W_edge + (size_t)w * 65536)
                              : (W_hop + (size_t)(w - 12) * 65536);
  f16* dst = Wout + (size_t)w * 65536;
  int c = threadIdx.x & 63;
  int r0 = threadIdx.x >> 6;
#pragma unroll
  for (int i = 0; i < 16; i++) {
    int r = i * 4 + r0;
    tile[r][c] = src[(size_t)(tk + r) * 256 + tn + c] * 16.0f;
  }
  __syncthreads();
#pragma unroll
  for (int i = 0; i < 16; i++) {
    int r = i * 4 + r0;
    dst[(size_t)(tn + r) * 256 + tk + c] = (f16)tile[c][r];
  }
}

// ---------------- x fp32 -> f16 copy ----------------

__global__ void k_xcast(const float* __restrict__ x, f16* __restrict__ xh) {
  size_t i = (size_t)(blockIdx.x * 256 + threadIdx.x) * 4;
  float4 v = *(const float4*)(x + i);
  f16x4v h = { (f16)v.x, (f16)v.y, (f16)v.z, (f16)v.w };
  *(f16x4v*)(xh + i) = h;
}

// ---------------- fused aggregation: one loop per (dst,etype), selector routing ----------------
// Wave per dst (4 waves/block). Per (dst,etype) segment [b0,b4): single
// 4-edge-per-iter loop; each row always adds into the etype acc; live hop
// accs get fma with selector in {0,1} from the row's position vs b1/b2/b3
// (sub-segments are contiguous by construction). Exact 0.0 adds for
// non-members; per-accumulator order preserved.

struct AggArgs {
  f16* out[6];   // etype0..2, hop2, hop3, hop4 (null = skip channel)
};

__global__ __launch_bounds__(256) void k_aggregate(
    const f16* __restrict__ xh,
    const int* __restrict__ crow12,
    const int* __restrict__ crec,
    AggArgs args)
{
  int wave = threadIdx.x >> 6;
  int lane = threadIdx.x & 63;
  int half = lane >> 5;
  int chunk = lane & 31;
  int v = blockIdx.x * 4 + wave;     // grid.x = NN/4
  const char* xb = (const char*)xh + chunk * 16;
  const bool doH2 = (args.out[3] != nullptr);
  const bool doH3 = (args.out[4] != nullptr);
  const bool doH4 = (args.out[5] != nullptr);
  const float s = 0.015625f;  // 2^-6

  float aH2[8], aH3[8], aH4[8];
#pragma unroll
  for (int j = 0; j < 8; j++) { aH2[j] = 0.f; aH3[j] = 0.f; aH4[j] = 0.f; }

#pragma unroll
  for (int et = 0; et < 3; et++) {
    int base = (v * 3 + et) * 4;
    int b0 = crow12[base], b1 = crow12[base + 1], b2 = crow12[base + 2],
        b3 = crow12[base + 3], b4 = crow12[base + 4];
    float aE[8];
#pragma unroll
    for (int j = 0; j < 8; j++) aE[j] = 0.f;

    int e = b0;
    for (; e + 4 <= b4; e += 4) {
      int i0 = e + half, i1 = e + 2 + half;
      int s0 = crec[i0], s1 = crec[i1];
      f16x8 h0 = *(const f16x8*)(xb + (size_t)s0 * 512);
      f16x8 h1 = *(const f16x8*)(xb + (size_t)s1 * 512);
      float r0[8], r1[8];
#pragma unroll
      for (int j = 0; j < 8; j++) {
        r0[j] = (float)h0[j];
        r1[j] = (float)h1[j];
        aE[j] += r0[j] + r1[j];
      }
      if (doH2) {
        float f0 = (i0 >= b1 && i0 < b2) ? 1.f : 0.f;
        float f1 = (i1 >= b1 && i1 < b2) ? 1.f : 0.f;
#pragma unroll
        for (int j = 0; j < 8; j++) aH2[j] += r0[j] * f0 + r1[j] * f1;
      }
      if (doH3) {
        float f0 = (i0 >= b2 && i0 < b3) ? 1.f : 0.f;
        float f1 = (i1 >= b2 && i1 < b3) ? 1.f : 0.f;
#pragma unroll
        for (int j = 0; j < 8; j++) aH3[j] += r0[j] * f0 + r1[j] * f1;
      }
      if (doH4) {
        float f0 = (i0 >= b3) ? 1.f : 0.f;
        float f1 = (i1 >= b3) ? 1.f : 0.f;
#pragma unroll
        for (int j = 0; j < 8; j++) aH4[j] += r0[j] * f0 + r1[j] * f1;
      }
    }
    if (e + 2 <= b4) {
      int i0 = e + half;
      int s0 = crec[i0];
      f16x8 h0 = *(const f16x8*)(xb + (size_t)s0 * 512);
      float r0[8];
#pragma unroll
      for (int j = 0; j < 8; j++) {
        r0[j] = (float)h0[j];
        aE[j] += r0[j];
      }
      if (doH2) {
        float f0 = (i0 >= b1 && i0 < b2) ? 1.f : 0.f;
#pragma unroll
        for (int j = 0; j < 8; j++) aH2[j] += r0[j] * f0;
      }
      if (doH3) {
        float f0 = (i0 >= b2 && i0 < b3) ? 1.f : 0.f;
#pragma unroll
        for (int j = 0; j < 8; j++) aH3[j] += r0[j] * f0;
      }
      if (doH4) {
        float f0 = (i0 >= b3) ? 1.f : 0.f;
#pragma unroll
        for (int j = 0; j < 8; j++) aH4[j] += r0[j] * f0;
      }
      e += 2;
    }
    if (e < b4 && half == 0) {
      int s0 = crec[e];
      f16x8 h0 = *(const f16x8*)(xb + (size_t)s0 * 512);
      float r0[8];
#pragma unroll
      for (int j = 0; j < 8; j++) {
        r0[j] = (float)h0[j];
        aE[j] += r0[j];
      }
      if (doH2) {
        float f0 = (e >= b1 && e < b2) ? 1.f : 0.f;
#pragma unroll
        for (int j = 0; j < 8; j++) aH2[j] += r0[j] * f0;
      }
      if (doH3) {
        float f0 = (e >= b2 && e < b3) ? 1.f : 0.f;
#pragma unroll
        for (int j = 0; j < 8; j++) aH3[j] += r0[j] * f0;
      }
      if (doH4) {
        float f0 = (e >= b3) ? 1.f : 0.f;
#pragma unroll
        for (int j = 0; j < 8; j++) aH4[j] += r0[j] * f0;
      }
    }

#pragma unroll
    for (int j = 0; j < 8; j++) aE[j] += __shfl_xor(aE[j], 32, 64);
    if (half == 0) {
      f16x8 o;
#pragma unroll
      for (int j = 0; j < 8; j++) o[j] = (f16)(aE[j] * s);
      *(f16x8*)((char*)args.out[et] + (size_t)v * 512 + chunk * 16) = o;
    }
  }

  if (doH2) {
#pragma unroll
    for (int j = 0; j < 8; j++) aH2[j] += __shfl_xor(aH2[j], 32, 64);
    if (half == 0) {
      f16x8 o;
#pragma unroll
      for (int j = 0; j < 8; j++) o[j] = (f16)(aH2[j] * s);
      *(f16x8*)((char*)args.out[3] + (size_t)v * 512 + chunk * 16) = o;
    }
  }
  if (doH3) {
#pragma unroll
    for (int j = 0; j < 8; j++) aH3[j] += __shfl_xor(aH3[j], 32, 64);
    if (half == 0) {
      f16x8 o;
#pragma unroll
      for (int j = 0; j < 8; j++) o[j] = (f16)(aH3[j] * s);
      *(f16x8*)((char*)args.out[4] + (size_t)v * 512 + chunk * 16) = o;
    }
  }
  if (doH4) {
#pragma unroll
    for (int j = 0; j < 8; j++) aH4[j] += __shfl_xor(aH4[j], 32, 64);
    if (half == 0) {
      f16x8 o;
#pragma unroll
      for (int j = 0; j < 8; j++) o[j] = (f16)(aH4[j] * s);
      *(f16x8*)((char*)args.out[5] + (size_t)v * 512 + chunk * 16) = o;
    }
  }
}

// ---------------- f16 MFMA GEMM: 64x128, BK=64, 8-wave counted-vmcnt dbuf ----------------
// (frozen at R25/R12 best: 512 threads / 8 waves, 2Mx4N, vmcnt(3) steady)

struct GemmArgs {
  const f16* A[6];     // aggregates, scale 2^-6 (row stride 512B, NROWP rows)
  const f16* W[6];     // transposed, scale 2^4
  const float* bias[6];
  const int*   cnt[6];
  int nch;
  int write_f32;       // 1 on final step
  const f16* xh_in;
  f16*       xh_out;
  float*     f32_out;
};

__global__ __launch_bounds__(512) void k_gemm(GemmArgs args) {
  __shared__ __align__(16) f16 sA[2][4096];   // 2 bufs x 8KB  : [ks][64][32]
  __shared__ __align__(16) f16 sB[2][8192];   // 2 bufs x 16KB : [ks][128][32]
  const int tid = threadIdx.x;
  const int lane = tid & 63;
  const int wave = tid >> 6;          // 0..7
  const int wm = (wave >> 2) * 32;    // 0 or 32
  const int wn = (wave & 3) * 32;     // 0,32,64,96
  const int m0 = blockIdx.x * 64;     // 313 blocks cover 20032 (padded)
  const int n0 = blockIdx.y * 128;
  const int nch = args.nch;
  const int Titer = nch * 4;          // BK=64 -> 4 iters per 256-K channel

  f32x4 acc[2][2];
#pragma unroll
  for (int mi = 0; mi < 2; mi++)
#pragma unroll
    for (int ni = 0; ni < 2; ni++) acc[mi][ni] = (f32x4){0.f, 0.f, 0.f, 0.f};

  int srcA, ldsAoffU;
  {
    int s = tid;                     // 512 chunks: [ks][64 rows][4 pc]
    int ks = s >> 8, r = (s >> 2) & 63, pc = s & 3;
    int lc = pc ^ ((r >> 1) & 3);
    srcA = r * 512 + ks * 64 + lc * 16;
    ldsAoffU = wave * 1024;          // + lane*16 implicit (linear dest)
  }
  int srcB[2], ldsBoffU[2];
#pragma unroll
  for (int i = 0; i < 2; i++) {
    int s = i * 512 + tid;           // 1024 chunks: [ks][128 rows][4 pc]
    int ks = s >> 9, r = (s >> 2) & 127, pc = s & 3;
    int lc = pc ^ ((r >> 1) & 3);
    srcB[i] = r * 512 + ks * 64 + lc * 16;
    ldsBoffU[i] = i * 8192 + wave * 1024;
  }

  const int fr = lane & 15;
  const int gq = lane >> 4;
  int offA[2][2], offB[2][2];        // [frag][ks]
#pragma unroll
  for (int mi = 0; mi < 2; mi++) {
    int rr = wm + mi * 16 + fr;
    int swz = (gq ^ ((rr >> 1) & 3)) << 4;
#pragma unroll
    for (int ks = 0; ks < 2; ks++) offA[mi][ks] = ks * 4096 + rr * 64 + swz;
  }
#pragma unroll
  for (int ni = 0; ni < 2; ni++) {
    int rr = wn + ni * 16 + fr;
    int swz = (gq ^ ((rr >> 1) & 3)) << 4;
#pragma unroll
    for (int ks = 0; ks < 2; ks++) offB[ni][ks] = ks * 8192 + rr * 64 + swz;
  }

  auto stage = [&](int buf, int j) {
    int c = j >> 2, kb = (j & 3) * 128;
    const char* pa = (const char*)args.A[c] + (size_t)m0 * 512 + kb;
    const char* pb = (const char*)args.W[c] + (size_t)n0 * 512 + kb;
    gload_lds16(pa + srcA, (char*)sA[buf] + ldsAoffU);
#pragma unroll
    for (int i = 0; i < 2; i++)
      gload_lds16(pb + srcB[i], (char*)sB[buf] + ldsBoffU[i]);
  };

  stage(0, 0);
  stage(1, 1);

  for (int j = 0; j < Titer; ++j) {
    const int p = j & 1;
    if (j + 1 < Titer) {
      asm volatile("s_waitcnt vmcnt(3)" ::: "memory");
    } else {
      asm volatile("s_waitcnt vmcnt(0)" ::: "memory");
    }
    __builtin_amdgcn_s_barrier();
    __builtin_amdgcn_sched_barrier(0);
    {
      f16x8 fA[2][2], fB[2][2];         // [ks][frag]
#pragma unroll
      for (int ks = 0; ks < 2; ks++) {
#pragma unroll
        for (int mi = 0; mi < 2; mi++)
          fA[ks][mi] = *(const f16x8*)((const char*)sA[p] + offA[mi][ks]);
#pragma unroll
        for (int ni = 0; ni < 2; ni++)
          fB[ks][ni] = *(const f16x8*)((const char*)sB[p] + offB[ni][ks]);
      }
#pragma unroll
      for (int ks = 0; ks < 2; ks++)
#pragma unroll
        for (int mi = 0; mi < 2; mi++)
#pragma unroll
          for (int ni = 0; ni < 2; ni++)
            acc[mi][ni] = __builtin_amdgcn_mfma_f32_16x16x32_f16(
                fA[ks][mi], fB[ks][ni], acc[mi][ni], 0, 0, 0);
    }
    __builtin_amdgcn_s_barrier();
    __builtin_amdgcn_sched_barrier(0);
    if (j + 2 < Titer) stage(p, j + 2);
  }

  // epilogue: out = xh + relu(acc*4 + sum_c cnt_c[row]*b_c[col]);  4 = 2^6*2^-4
  float bcol[2][6];
#pragma unroll
  for (int ni = 0; ni < 2; ni++) {
    int gcol = n0 + wn + ni * 16 + fr;
#pragma unroll
    for (int c = 0; c < 6; c++)
      bcol[ni][c] = (c < nch) ? args.bias[c][gcol] : 0.f;
  }
  const int rowq = gq * 4;
#pragma unroll
  for (int mi = 0; mi < 2; mi++) {
#pragma unroll
    for (int rI = 0; rI < 4; rI++) {
      int grow = m0 + wm + mi * 16 + rowq + rI;
      if (grow < NN) {
        float cv[6];
#pragma unroll
        for (int c = 0; c < 6; c++)
          cv[c] = (c < nch) ? (float)args.cnt[c][grow] : 0.f;
        size_t rowoff = (size_t)grow * DD;
#pragma unroll
        for (int ni = 0; ni < 2; ni++) {
          int gcol = n0 + wn + ni * 16 + fr;
          float v = acc[mi][ni][rI] * 4.0f;
#pragma unroll
          for (int c = 0; c < 6; c++) v += cv[c] * bcol[ni][c];
          float outv = (float)args.xh_in[rowoff + gcol] + fmaxf(v, 0.f);
          args.xh_out[rowoff + gcol] = (f16)outv;
          if (args.write_f32) args.f32_out[rowoff + gcol] = outv;
        }
      }
    }
  }
}

// ---------------- host ----------------

extern "C" void kernel_launch(void* const* d_in, const int* in_sizes, int n_in,
                              void* d_out, int out_size, void* d_ws, size_t ws_size,
                              hipStream_t stream) {
  const float* x      = (const float*)d_in[0];
  const int* edge_index = (const int*)d_in[1];
  const int* edge_attr  = (const int*)d_in[2];
  const float* W_edge = (const float*)d_in[3];
  const float* b_edge = (const float*)d_in[4];
  const float* W_hop  = (const float*)d_in[5];
  const float* b_hop  = (const float*)d_in[6];
  float* out = (float*)d_out;

  // workspace layout
  char* ws = (char*)d_ws;
  int* cnt    = (int*)ws;                  // 6N   (GEMM bias counts)
  int* crow12 = cnt + 6 * NN;              // 12N+1
  int* ccur12 = crow12 + SCANN + 1;        // 12N (histogram, then positions)
  int* bsum   = ccur12 + SCANN;            // NB12
  int* crec   = bsum + NB12;               // NE
  size_t int_count = (size_t)6 * NN + (SCANN + 1) + SCANN + NB12 + (size_t)NE;
  const size_t ND  = (size_t)NN * DD;
  const size_t NDP = (size_t)NROWP * DD;   // padded stride for GEMM A-tiles
  f16* Wsplit = (f16*)(ws + ((int_count * 4 + 255) & ~(size_t)255));  // 24 * 65536 f16
  f16* xh = Wsplit + (size_t)24 * 65536;                              // N*D f16
  f16* aggBase = xh + ND;
  f16* agg[9];
  for (int i = 0; i < 9; i++) agg[i] = aggBase + (size_t)i * NDP;
  f16** Cb = agg + 3;  // Cb[0..5]: C2_s0,C2_s1,C2_s2, C3_s0,C3_s1, C4_s0

  hipMemsetAsync(ccur12, 0, SCANN * sizeof(int), stream);

  k_hist<<<(NE + 255) / 256, 256, 0, stream>>>(edge_index, edge_attr, ccur12);
  k_scan_blk<<<NB12, 1024, 0, stream>>>(ccur12, crow12, bsum);
  k_scan_top<<<1, 256, 0, stream>>>(bsum, crow12);
  k_scan_fix<<<NB12, 1024, 0, stream>>>(crow12, ccur12, bsum);
  k_scatter<<<(NE + 255) / 256, 256, 0, stream>>>(edge_index, edge_attr, ccur12, crec);
  k_cnt6<<<(NN + 255) / 256, 256, 0, stream>>>(crow12, cnt);
  k_wsplit<<<dim3(4, 4, 24), 256, 0, stream>>>(W_edge, W_hop, Wsplit);
  k_xcast<<<ND / 1024, 256, 0, stream>>>(x, xh);

  for (int t = 0; t < TT; ++t) {
    AggArgs aa{};
    aa.out[0] = agg[0];
    aa.out[1] = agg[1];
    aa.out[2] = agg[2];
    aa.out[3] = (t <= 2) ? Cb[t]     : nullptr;   // hop2 of step t
    aa.out[4] = (t <= 1) ? Cb[3 + t] : nullptr;   // hop3 of step t
    aa.out[5] = (t == 0) ? Cb[5]     : nullptr;   // hop4 of step t
    k_aggregate<<<dim3(NN / 4), 256, 0, stream>>>(xh, crow12, crec, aa);

    GemmArgs ga{};
    for (int e = 0; e < NT; ++e) {
      ga.A[e]    = agg[e];
      ga.W[e]    = Wsplit + (size_t)(t * NT + e) * 65536;
      ga.bias[e] = b_edge + (size_t)(t * NT + e) * DD;
      ga.cnt[e]  = cnt + (size_t)e * NN;
    }
    int nc = NT;
    for (int k = 2; k <= t + 1; ++k) {
      int s = t + 1 - k;
      ga.A[nc]    = (k == 2) ? Cb[s] : (k == 3) ? Cb[3 + s] : Cb[5];
      ga.W[nc]    = Wsplit + (size_t)(12 + t * 3 + (k - 2)) * 65536;
      ga.bias[nc] = b_hop + (size_t)(t * (TT - 1) + (k - 2)) * DD;
      ga.cnt[nc]  = cnt + (size_t)(3 + (k - 2)) * NN;
      nc++;
    }
    for (int c = nc; c < 6; ++c) {
      ga.A[c] = ga.A[0]; ga.W[c] = ga.W[0]; ga.bias[c] = ga.bias[0]; ga.cnt[c] = ga.cnt[0];
    }
    ga.nch = nc;
    ga.write_f32 = (t == TT - 1) ? 1 : 0;
    ga.xh_in  = xh;
    ga.xh_out = xh;
    ga.f32_out = out;
    k_gemm<<<dim3(313, 2), 512, 0, stream>>>(ga);
  }
}

// Round 14
// 469.818 us; speedup vs baseline: 1.0347x; 1.0347x over previous
//
#include <hip/hip_runtime.h>

// RelationalDelayGNNStage: N=20000, E=500000, D=256, T=4, NTYPES=3
// Round 27: revert R26's selector-aggregate (486us, slight regression —
// aggregate is latency-bound on ~2-edge sub-segments; loop shape neutral)
// back to R25-best GSEG; add T1 pair-then-XCD-swizzle to the gemm grid.
// R25 profile: FETCH 68.7MB ~ A fetched twice (the two N-half blocks of
// each M-strip land on different XCDs) and B re-fetched across XCD L2s.
// Now: flat 626-block grid, bijective XCD swizzle (m204: q=78,r=2), then
// m0=(wg>>1)*64, n0=(wg&1)*128 — N-half pairs adjacent in the same XCD
// chunk (A once/XCD; 39 M-tiles' B = 786KB << 4MB L2). Mapping-only:
// bit-identical output. Everything else frozen at R25 (478.8us best).
// Numerics: f16 operands (A 2^-6, W 2^4), fp32 accum; absmax fp32-reorder
// floor (budget 174).

#define NN 20000
#define NROWP 20032   // 64-row-tile padded row count
#define NE 500000
#define DD 256
#define TT 4
#define NT 3
#define SCANN (12 * NN)          // 240000 sub-channel counters
#define NB12 235                 // ceil(SCANN / 1024)

typedef _Float16 f16;
typedef _Float16 f16x8 __attribute__((ext_vector_type(8)));
typedef _Float16 f16x4v __attribute__((ext_vector_type(4)));
typedef float f32x4 __attribute__((ext_vector_type(4)));

__device__ __forceinline__ void gload_lds16(const void* g, void* l) {
  __builtin_amdgcn_global_load_lds(
      (const __attribute__((address_space(1))) unsigned int*)g,
      (__attribute__((address_space(3))) unsigned int*)l, 16, 0, 0);
}

// ---------------- 12-sub-channel CSR build ----------------
// key = ((dst*3 + etype) << 2) | (hop-1);  hop in 1..4

__global__ void k_hist(const int* __restrict__ ei, const int* __restrict__ ea,
                       int* __restrict__ cnt12) {
  int e = blockIdx.x * 256 + threadIdx.x;
  if (e >= NE) return;
  int dst = ei[NE + e];
  int hop = ea[2 * e];
  int et  = ea[2 * e + 1];
  atomicAdd(&cnt12[((dst * 3 + et) << 2) | (hop - 1)], 1);
}

// hierarchical scan over cnt12[12N] -> crow12 (exclusive), ccur copy

__global__ __launch_bounds__(1024) void k_scan_blk(
    const int* __restrict__ cnt, int* __restrict__ crow, int* __restrict__ bsum) {
  __shared__ int wsum[16];
  int tid = threadIdx.x, lane = tid & 63, wv = tid >> 6;
  int i = blockIdx.x * 1024 + tid;
  int v = (i < SCANN) ? cnt[i] : 0;
  int s = v;
#pragma unroll
  for (int off = 1; off < 64; off <<= 1) {
    int t = __shfl_up(s, off, 64);
    if (lane >= off) s += t;
  }
  if (lane == 63) wsum[wv] = s;
  __syncthreads();
  if (wv == 0) {
    int ws = (lane < 16) ? wsum[lane] : 0;
#pragma unroll
    for (int off = 1; off < 16; off <<= 1) {
      int t = __shfl_up(ws, off, 64);
      if (lane >= off) ws += t;
    }
    if (lane < 16) wsum[lane] = ws;
  }
  __syncthreads();
  int excl = ((wv == 0) ? 0 : wsum[wv - 1]) + s - v;
  if (i < SCANN) crow[i] = excl;
  if (tid == 1023) bsum[blockIdx.x] = wsum[15];
}

__global__ __launch_bounds__(256) void k_scan_top(
    int* __restrict__ bsum, int* __restrict__ crow) {
  __shared__ int wsum2[4];
  int tid = threadIdx.x, lane = tid & 63, wv = tid >> 6;
  int v = (tid < NB12) ? bsum[tid] : 0;
  int s = v;
#pragma unroll
  for (int off = 1; off < 64; off <<= 1) {
    int t = __shfl_up(s, off, 64);
    if (lane >= off) s += t;
  }
  if (lane == 63) wsum2[wv] = s;
  __syncthreads();
  int add = 0;
#pragma unroll
  for (int w = 0; w < 4; w++) add += (w < wv) ? wsum2[w] : 0;
  int excl = add + s - v;
  if (tid < NB12) bsum[tid] = excl;
  if (tid == NB12 - 1) crow[SCANN] = excl + v;
}

__global__ __launch_bounds__(1024) void k_scan_fix(
    int* __restrict__ crow, int* __restrict__ ccur, const int* __restrict__ bsum) {
  int i = blockIdx.x * 1024 + threadIdx.x;
  if (i >= SCANN) return;
  int val = crow[i] + bsum[blockIdx.x];
  crow[i] = val;
  ccur[i] = val;
}

__global__ void k_scatter(const int* __restrict__ ei, const int* __restrict__ ea,
                          int* __restrict__ ccur, int* __restrict__ crec) {
  int e = blockIdx.x * 256 + threadIdx.x;
  if (e >= NE) return;
  int src = ei[e];
  int dst = ei[NE + e];
  int hop = ea[2 * e];
  int et  = ea[2 * e + 1];
  int pos = atomicAdd(&ccur[((dst * 3 + et) << 2) | (hop - 1)], 1);
  crec[pos] = src;
}

// per-(node,channel) counts for the GEMM bias epilogue, from crow12

__global__ __launch_bounds__(256) void k_cnt6(
    const int* __restrict__ crow12, int* __restrict__ cnt) {
  int v = blockIdx.x * 256 + threadIdx.x;
  if (v >= NN) return;
  int h2 = 0, h3 = 0, h4 = 0;
#pragma unroll
  for (int et = 0; et < 3; et++) {
    int base = (v * 3 + et) * 4;
    int b0 = crow12[base], b1 = crow12[base + 1], b2 = crow12[base + 2],
        b3 = crow12[base + 3], b4 = crow12[base + 4];
    cnt[et * NN + v] = b4 - b0;
    h2 += b2 - b1;
    h3 += b3 - b2;
    h4 += b4 - b3;
  }
  cnt[3 * NN + v] = h2;
  cnt[4 * NN + v] = h3;
  cnt[5 * NN + v] = h4;
}

// ---------------- W: fp32 -> transposed f16 (scale 2^4), LDS-tiled ----------------

__global__ __launch_bounds__(256) void k_wsplit(
    const float* __restrict__ W_edge, const float* __restrict__ W_hop,
    f16* __restrict__ Wout) {
  __shared__ float tile[64][65];
  int w = blockIdx.z;
  int tk = blockIdx.x * 64;
  int tn = blockIdx.y * 64;
  const float* src = (w < 12) ? (W_edge + (size_t)w * 65536)
                              : (W_hop + (size_t)(w - 12) * 65536);
  f16* dst = Wout + (size_t)w * 65536;
  int c = threadIdx.x & 63;
  int r0 = threadIdx.x >> 6;
#pragma unroll
  for (int i = 0; i < 16; i++) {
    int r = i * 4 + r0;
    tile[r][c] = src[(size_t)(tk + r) * 256 + tn + c] * 16.0f;
  }
  __syncthreads();
#pragma unroll
  for (int i = 0; i < 16; i++) {
    int r = i * 4 + r0;
    dst[(size_t)(tn + r) * 256 + tk + c] = (f16)tile[c][r];
  }
}

// ---------------- x fp32 -> f16 copy ----------------

__global__ void k_xcast(const float* __restrict__ x, f16* __restrict__ xh) {
  size_t i = (size_t)(blockIdx.x * 256 + threadIdx.x) * 4;
  float4 v = *(const float4*)(x + i);
  f16x4v h = { (f16)v.x, (f16)v.y, (f16)v.z, (f16)v.w };
  *(f16x4v*)(xh + i) = h;
}

// ---------------- fused aggregation: one gather per edge, 2 accs ----------------
// (R25-best GSEG version)

struct AggArgs {
  f16* out[6];   // etype0..2, hop2, hop3, hop4 (null = skip channel)
};

#define GSEG(LO, HI, DOH, ACCH)                                         \
  {                                                                     \
    int e_ = (LO);                                                      \
    for (; e_ + 4 <= (HI); e_ += 4) {                                   \
      int s0_ = crec[e_ + half], s1_ = crec[e_ + 2 + half];             \
      f16x8 h0_ = *(const f16x8*)(xb + (size_t)s0_ * 512);              \
      f16x8 h1_ = *(const f16x8*)(xb + (size_t)s1_ * 512);              \
      float tb_[8];                                                     \
      _Pragma("unroll") for (int j = 0; j < 8; j++) {                   \
        tb_[j] = (float)h0_[j] + (float)h1_[j];                         \
        aE[j] += tb_[j];                                                \
      }                                                                 \
      if (DOH) {                                                        \
        _Pragma("unroll") for (int j = 0; j < 8; j++) ACCH[j] += tb_[j];\
      }                                                                 \
    }                                                                   \
    if (e_ + 2 <= (HI)) {                                               \
      int s0_ = crec[e_ + half];                                        \
      f16x8 h0_ = *(const f16x8*)(xb + (size_t)s0_ * 512);              \
      float tb_[8];                                                     \
      _Pragma("unroll") for (int j = 0; j < 8; j++) {                   \
        tb_[j] = (float)h0_[j];                                         \
        aE[j] += tb_[j];                                                \
      }                                                                 \
      if (DOH) {                                                        \
        _Pragma("unroll") for (int j = 0; j < 8; j++) ACCH[j] += tb_[j];\
      }                                                                 \
      e_ += 2;                                                          \
    }                                                                   \
    if (e_ < (HI) && half == 0) {                                       \
      int s0_ = crec[e_];                                               \
      f16x8 h0_ = *(const f16x8*)(xb + (size_t)s0_ * 512);              \
      float tb_[8];                                                     \
      _Pragma("unroll") for (int j = 0; j < 8; j++) {                   \
        tb_[j] = (float)h0_[j];                                         \
        aE[j] += tb_[j];                                                \
      }                                                                 \
      if (DOH) {                                                        \
        _Pragma("unroll") for (int j = 0; j < 8; j++) ACCH[j] += tb_[j];\
      }                                                                 \
    }                                                                   \
  }

__global__ __launch_bounds__(256) void k_aggregate(
    const f16* __restrict__ xh,
    const int* __restrict__ crow12,
    const int* __restrict__ crec,
    AggArgs args)
{
  int wave = threadIdx.x >> 6;
  int lane = threadIdx.x & 63;
  int half = lane >> 5;
  int chunk = lane & 31;
  int v = blockIdx.x * 4 + wave;     // grid.x = NN/4
  const char* xb = (const char*)xh + chunk * 16;
  const bool doH2 = (args.out[3] != nullptr);
  const bool doH3 = (args.out[4] != nullptr);
  const bool doH4 = (args.out[5] != nullptr);
  const float s = 0.015625f;  // 2^-6

  float aH2[8], aH3[8], aH4[8];
#pragma unroll
  for (int j = 0; j < 8; j++) { aH2[j] = 0.f; aH3[j] = 0.f; aH4[j] = 0.f; }

#pragma unroll
  for (int et = 0; et < 3; et++) {
    int base = (v * 3 + et) * 4;
    int b0 = crow12[base], b1 = crow12[base + 1], b2 = crow12[base + 2],
        b3 = crow12[base + 3], b4 = crow12[base + 4];
    float aE[8];
#pragma unroll
    for (int j = 0; j < 8; j++) aE[j] = 0.f;
    GSEG(b0, b1, false, aH2);
    GSEG(b1, b2, doH2, aH2);
    GSEG(b2, b3, doH3, aH3);
    GSEG(b3, b4, doH4, aH4);
#pragma unroll
    for (int j = 0; j < 8; j++) aE[j] += __shfl_xor(aE[j], 32, 64);
    if (half == 0) {
      f16x8 o;
#pragma unroll
      for (int j = 0; j < 8; j++) o[j] = (f16)(aE[j] * s);
      *(f16x8*)((char*)args.out[et] + (size_t)v * 512 + chunk * 16) = o;
    }
  }

  if (doH2) {
#pragma unroll
    for (int j = 0; j < 8; j++) aH2[j] += __shfl_xor(aH2[j], 32, 64);
    if (half == 0) {
      f16x8 o;
#pragma unroll
      for (int j = 0; j < 8; j++) o[j] = (f16)(aH2[j] * s);
      *(f16x8*)((char*)args.out[3] + (size_t)v * 512 + chunk * 16) = o;
    }
  }
  if (doH3) {
#pragma unroll
    for (int j = 0; j < 8; j++) aH3[j] += __shfl_xor(aH3[j], 32, 64);
    if (half == 0) {
      f16x8 o;
#pragma unroll
      for (int j = 0; j < 8; j++) o[j] = (f16)(aH3[j] * s);
      *(f16x8*)((char*)args.out[4] + (size_t)v * 512 + chunk * 16) = o;
    }
  }
  if (doH4) {
#pragma unroll
    for (int j = 0; j < 8; j++) aH4[j] += __shfl_xor(aH4[j], 32, 64);
    if (half == 0) {
      f16x8 o;
#pragma unroll
      for (int j = 0; j < 8; j++) o[j] = (f16)(aH4[j] * s);
      *(f16x8*)((char*)args.out[5] + (size_t)v * 512 + chunk * 16) = o;
    }
  }
}

// ---------------- f16 MFMA GEMM: 64x128, BK=64, 8-wave counted-vmcnt dbuf ----------------
// R25-best structure + T1 pair-then-XCD swizzle: flat 626-block grid;
// bijective XCD remap (m204, q=78, r=2); m0=(wg>>1)*64, n0=(wg&1)*128 so
// both N-halves of an M-strip are adjacent in the same XCD chunk (A rows
// fetched once per XCD; each XCD's B working set 786KB << 4MB L2).

struct GemmArgs {
  const f16* A[6];     // aggregates, scale 2^-6 (row stride 512B, NROWP rows)
  const f16* W[6];     // transposed, scale 2^4
  const float* bias[6];
  const int*   cnt[6];
  int nch;
  int write_f32;       // 1 on final step
  const f16* xh_in;
  f16*       xh_out;
  float*     f32_out;
};

__global__ __launch_bounds__(512) void k_gemm(GemmArgs args) {
  __shared__ __align__(16) f16 sA[2][4096];   // 2 bufs x 8KB  : [ks][64][32]
  __shared__ __align__(16) f16 sB[2][8192];   // 2 bufs x 16KB : [ks][128][32]
  const int tid = threadIdx.x;
  const int lane = tid & 63;
  const int wave = tid >> 6;          // 0..7
  const int wm = (wave >> 2) * 32;    // 0 or 32
  const int wn = (wave & 3) * 32;     // 0,32,64,96

  // T1: bijective XCD swizzle over 626 blocks (q=78, r=2), N-half pairs adjacent
  const int orig = blockIdx.x;
  const int xcd = orig & 7, idx = orig >> 3;
  const int wg = (xcd < 2 ? xcd * 79 : 158 + (xcd - 2) * 78) + idx;
  const int m0 = (wg >> 1) * 64;      // 313 strips cover 20032 (padded)
  const int n0 = (wg & 1) * 128;
  const int nch = args.nch;
  const int Titer = nch * 4;          // BK=64 -> 4 iters per 256-K channel

  f32x4 acc[2][2];
#pragma unroll
  for (int mi = 0; mi < 2; mi++)
#pragma unroll
    for (int ni = 0; ni < 2; ni++) acc[mi][ni] = (f32x4){0.f, 0.f, 0.f, 0.f};

  int srcA, ldsAoffU;
  {
    int s = tid;                     // 512 chunks: [ks][64 rows][4 pc]
    int ks = s >> 8, r = (s >> 2) & 63, pc = s & 3;
    int lc = pc ^ ((r >> 1) & 3);
    srcA = r * 512 + ks * 64 + lc * 16;
    ldsAoffU = wave * 1024;          // + lane*16 implicit (linear dest)
  }
  int srcB[2], ldsBoffU[2];
#pragma unroll
  for (int i = 0; i < 2; i++) {
    int s = i * 512 + tid;           // 1024 chunks: [ks][128 rows][4 pc]
    int ks = s >> 9, r = (s >> 2) & 127, pc = s & 3;
    int lc = pc ^ ((r >> 1) & 3);
    srcB[i] = r * 512 + ks * 64 + lc * 16;
    ldsBoffU[i] = i * 8192 + wave * 1024;
  }

  const int fr = lane & 15;
  const int gq = lane >> 4;
  int offA[2][2], offB[2][2];        // [frag][ks]
#pragma unroll
  for (int mi = 0; mi < 2; mi++) {
    int rr = wm + mi * 16 + fr;
    int swz = (gq ^ ((rr >> 1) & 3)) << 4;
#pragma unroll
    for (int ks = 0; ks < 2; ks++) offA[mi][ks] = ks * 4096 + rr * 64 + swz;
  }
#pragma unroll
  for (int ni = 0; ni < 2; ni++) {
    int rr = wn + ni * 16 + fr;
    int swz = (gq ^ ((rr >> 1) & 3)) << 4;
#pragma unroll
    for (int ks = 0; ks < 2; ks++) offB[ni][ks] = ks * 8192 + rr * 64 + swz;
  }

  auto stage = [&](int buf, int j) {
    int c = j >> 2, kb = (j & 3) * 128;
    const char* pa = (const char*)args.A[c] + (size_t)m0 * 512 + kb;
    const char* pb = (const char*)args.W[c] + (size_t)n0 * 512 + kb;
    gload_lds16(pa + srcA, (char*)sA[buf] + ldsAoffU);
#pragma unroll
    for (int i = 0; i < 2; i++)
      gload_lds16(pb + srcB[i], (char*)sB[buf] + ldsBoffU[i]);
  };

  stage(0, 0);
  stage(1, 1);

  for (int j = 0; j < Titer; ++j) {
    const int p = j & 1;
    if (j + 1 < Titer) {
      asm volatile("s_waitcnt vmcnt(3)" ::: "memory");
    } else {
      asm volatile("s_waitcnt vmcnt(0)" ::: "memory");
    }
    __builtin_amdgcn_s_barrier();
    __builtin_amdgcn_sched_barrier(0);
    {
      f16x8 fA[2][2], fB[2][2];         // [ks][frag]
#pragma unroll
      for (int ks = 0; ks < 2; ks++) {
#pragma unroll
        for (int mi = 0; mi < 2; mi++)
          fA[ks][mi] = *(const f16x8*)((const char*)sA[p] + offA[mi][ks]);
#pragma unroll
        for (int ni = 0; ni < 2; ni++)
          fB[ks][ni] = *(const f16x8*)((const char*)sB[p] + offB[ni][ks]);
      }
#pragma unroll
      for (int ks = 0; ks < 2; ks++)
#pragma unroll
        for (int mi = 0; mi < 2; mi++)
#pragma unroll
          for (int ni = 0; ni < 2; ni++)
            acc[mi][ni] = __builtin_amdgcn_mfma_f32_16x16x32_f16(
                fA[ks][mi], fB[ks][ni], acc[mi][ni], 0, 0, 0);
    }
    __builtin_amdgcn_s_barrier();
    __builtin_amdgcn_sched_barrier(0);
    if (j + 2 < Titer) stage(p, j + 2);
  }

  // epilogue: out = xh + relu(acc*4 + sum_c cnt_c[row]*b_c[col]);  4 = 2^6*2^-4
  float bcol[2][6];
#pragma unroll
  for (int ni = 0; ni < 2; ni++) {
    int gcol = n0 + wn + ni * 16 + fr;
#pragma unroll
    for (int c = 0; c < 6; c++)
      bcol[ni][c] = (c < nch) ? args.bias[c][gcol] : 0.f;
  }
  const int rowq = gq * 4;
#pragma unroll
  for (int mi = 0; mi < 2; mi++) {
#pragma unroll
    for (int rI = 0; rI < 4; rI++) {
      int grow = m0 + wm + mi * 16 + rowq + rI;
      if (grow < NN) {
        float cv[6];
#pragma unroll
        for (int c = 0; c < 6; c++)
          cv[c] = (c < nch) ? (float)args.cnt[c][grow] : 0.f;
        size_t rowoff = (size_t)grow * DD;
#pragma unroll
        for (int ni = 0; ni < 2; ni++) {
          int gcol = n0 + wn + ni * 16 + fr;
          float v = acc[mi][ni][rI] * 4.0f;
#pragma unroll
          for (int c = 0; c < 6; c++) v += cv[c] * bcol[ni][c];
          float outv = (float)args.xh_in[rowoff + gcol] + fmaxf(v, 0.f);
          args.xh_out[rowoff + gcol] = (f16)outv;
          if (args.write_f32) args.f32_out[rowoff + gcol] = outv;
        }
      }
    }
  }
}

// ---------------- host ----------------

extern "C" void kernel_launch(void* const* d_in, const int* in_sizes, int n_in,
                              void* d_out, int out_size, void* d_ws, size_t ws_size,
                              hipStream_t stream) {
  const float* x      = (const float*)d_in[0];
  const int* edge_index = (const int*)d_in[1];
  const int* edge_attr  = (const int*)d_in[2];
  const float* W_edge = (const float*)d_in[3];
  const float* b_edge = (const float*)d_in[4];
  const float* W_hop  = (const float*)d_in[5];
  const float* b_hop  = (const float*)d_in[6];
  float* out = (float*)d_out;

  // workspace layout
  char* ws = (char*)d_ws;
  int* cnt    = (int*)ws;                  // 6N   (GEMM bias counts)
  int* crow12 = cnt + 6 * NN;              // 12N+1
  int* ccur12 = crow12 + SCANN + 1;        // 12N (histogram, then positions)
  int* bsum   = ccur12 + SCANN;            // NB12
  int* crec   = bsum + NB12;               // NE
  size_t int_count = (size_t)6 * NN + (SCANN + 1) + SCANN + NB12 + (size_t)NE;
  const size_t ND  = (size_t)NN * DD;
  const size_t NDP = (size_t)NROWP * DD;   // padded stride for GEMM A-tiles
  f16* Wsplit = (f16*)(ws + ((int_count * 4 + 255) & ~(size_t)255));  // 24 * 65536 f16
  f16* xh = Wsplit + (size_t)24 * 65536;                              // N*D f16
  f16* aggBase = xh + ND;
  f16* agg[9];
  for (int i = 0; i < 9; i++) agg[i] = aggBase + (size_t)i * NDP;
  f16** Cb = agg + 3;  // Cb[0..5]: C2_s0,C2_s1,C2_s2, C3_s0,C3_s1, C4_s0

  hipMemsetAsync(ccur12, 0, SCANN * sizeof(int), stream);

  k_hist<<<(NE + 255) / 256, 256, 0, stream>>>(edge_index, edge_attr, ccur12);
  k_scan_blk<<<NB12, 1024, 0, stream>>>(ccur12, crow12, bsum);
  k_scan_top<<<1, 256, 0, stream>>>(bsum, crow12);
  k_scan_fix<<<NB12, 1024, 0, stream>>>(crow12, ccur12, bsum);
  k_scatter<<<(NE + 255) / 256, 256, 0, stream>>>(edge_index, edge_attr, ccur12, crec);
  k_cnt6<<<(NN + 255) / 256, 256, 0, stream>>>(crow12, cnt);
  k_wsplit<<<dim3(4, 4, 24), 256, 0, stream>>>(W_edge, W_hop, Wsplit);
  k_xcast<<<ND / 1024, 256, 0, stream>>>(x, xh);

  for (int t = 0; t < TT; ++t) {
    AggArgs aa{};
    aa.out[0] = agg[0];
    aa.out[1] = agg[1];
    aa.out[2] = agg[2];
    aa.out[3] = (t <= 2) ? Cb[t]     : nullptr;   // hop2 of step t
    aa.out[4] = (t <= 1) ? Cb[3 + t] : nullptr;   // hop3 of step t
    aa.out[5] = (t == 0) ? Cb[5]     : nullptr;   // hop4 of step t
    k_aggregate<<<dim3(NN / 4), 256, 0, stream>>>(xh, crow12, crec, aa);

    GemmArgs ga{};
    for (int e = 0; e < NT; ++e) {
      ga.A[e]    = agg[e];
      ga.W[e]    = Wsplit + (size_t)(t * NT + e) * 65536;
      ga.bias[e] = b_edge + (size_t)(t * NT + e) * DD;
      ga.cnt[e]  = cnt + (size_t)e * NN;
    }
    int nc = NT;
    for (int k = 2; k <= t + 1; ++k) {
      int s = t + 1 - k;
      ga.A[nc]    = (k == 2) ? Cb[s] : (k == 3) ? Cb[3 + s] : Cb[5];
      ga.W[nc]    = Wsplit + (size_t)(12 + t * 3 + (k - 2)) * 65536;
      ga.bias[nc] = b_hop + (size_t)(t * (TT - 1) + (k - 2)) * DD;
      ga.cnt[nc]  = cnt + (size_t)(3 + (k - 2)) * NN;
      nc++;
    }
    for (int c = nc; c < 6; ++c) {
      ga.A[c] = ga.A[0]; ga.W[c] = ga.W[0]; ga.bias[c] = ga.bias[0]; ga.cnt[c] = ga.cnt[0];
    }
    ga.nch = nc;
    ga.write_f32 = (t == TT - 1) ? 1 : 0;
    ga.xh_in  = xh;
    ga.xh_out = xh;
    ga.f32_out = out;
    k_gemm<<<dim3(626), 512, 0, stream>>>(ga);
  }
}